// Round 1
// baseline (4371.832 us; speedup 1.0000x reference)
//
#include <hip/hip_runtime.h>
#include <hip/hip_bf16.h>
#include <cstdint>

// AttentionDecoder: B=128, L=196, T_dec=31, E=H=F=A=512, V=10000
// Out layout: logits (128*31*10000) | alphas (128*31*196) | dec_len (128), fp32.

#define DEV __device__ __forceinline__

DEV float sigmf(float v) { return 1.f / (1.f + expf(-v)); }
DEV float actf(float v, int act) {
  if (act == 1) return sigmf(v);
  if (act == 2) return tanhf(v);
  return v;
}

// ---------------------------------------------------------------------------
// Tiled fp32 GEMM body: C(MxN) = act(A(MxK) @ W(NxK)^T + bias)
// tile 32x64 (BM=32,BN=64,BK=32), 256 threads, TM=2,TN=4.
// Requires M%32==0, N%64==0, K%32==0, lda/ldw multiples of 4.
// LDS layout k-major with +4 pad: As[kk][r] stride 36, Ws[kk][c] stride 68.
DEV void gemm32_body(float* As, float* Ws, int mt, int nt,
                     const float* __restrict__ A, int lda,
                     const float* __restrict__ W, int ldw,
                     const float* __restrict__ bias,
                     float* __restrict__ C, int ldc, int K, int act)
{
  const int tid = threadIdx.x;
  const int m0 = mt * 32, n0 = nt * 64;
  const int tx = tid & 15, ty = tid >> 4;
  const int r0 = ty * 2, c0 = tx * 4;
  const int lr = tid >> 3;        // 0..31
  const int lk = (tid & 7) * 4;   // 0,4,..,28
  const float* Ap  = A + (size_t)(m0 + lr) * lda + lk;
  const float* Wp0 = W + (size_t)(n0 + lr) * ldw + lk;
  const float* Wp1 = W + (size_t)(n0 + lr + 32) * ldw + lk;
  float acc[2][4] = {{0.f,0.f,0.f,0.f},{0.f,0.f,0.f,0.f}};
  for (int k0 = 0; k0 < K; k0 += 32) {
    float4 av = *(const float4*)(Ap + k0);
    float4 w0 = *(const float4*)(Wp0 + k0);
    float4 w1 = *(const float4*)(Wp1 + k0);
    __syncthreads();
    As[(lk+0)*36 + lr] = av.x;
    As[(lk+1)*36 + lr] = av.y;
    As[(lk+2)*36 + lr] = av.z;
    As[(lk+3)*36 + lr] = av.w;
    Ws[(lk+0)*68 + lr] = w0.x;
    Ws[(lk+1)*68 + lr] = w0.y;
    Ws[(lk+2)*68 + lr] = w0.z;
    Ws[(lk+3)*68 + lr] = w0.w;
    Ws[(lk+0)*68 + lr + 32] = w1.x;
    Ws[(lk+1)*68 + lr + 32] = w1.y;
    Ws[(lk+2)*68 + lr + 32] = w1.z;
    Ws[(lk+3)*68 + lr + 32] = w1.w;
    __syncthreads();
#pragma unroll
    for (int kk = 0; kk < 32; ++kk) {
      float2 a = *(const float2*)&As[kk*36 + r0];
      float4 w = *(const float4*)&Ws[kk*68 + c0];
      const float aa[2] = {a.x, a.y};
      const float* wwp = (const float*)&w;
#pragma unroll
      for (int i = 0; i < 2; ++i)
#pragma unroll
        for (int j = 0; j < 4; ++j)
          acc[i][j] = fmaf(aa[i], wwp[j], acc[i][j]);
    }
  }
#pragma unroll
  for (int i = 0; i < 2; ++i)
#pragma unroll
    for (int j = 0; j < 4; ++j) {
      float v = acc[i][j];
      if (bias) v += bias[n0 + c0 + j];
      C[(size_t)(m0 + r0 + i) * ldc + n0 + c0 + j] = actf(v, act);
    }
}

__global__ __launch_bounds__(256) void gemm32_k(
    const float* __restrict__ A, int lda, const float* __restrict__ W, int ldw,
    const float* __restrict__ bias, float* __restrict__ C, int ldc, int K, int act)
{
  __shared__ float As[32*36];
  __shared__ float Ws[32*68];
  gemm32_body(As, Ws, blockIdx.y, blockIdx.x, A, lda, W, ldw, bias, C, ldc, K, act);
}

// ---------------------------------------------------------------------------
// 64x64 tile fp32 GEMM. LOGITS variant remaps rows (t,b) -> out[b,t,:] with
// mask (t < declen[b]) and handles N=10000 edge. Non-logits requires N%64==0.
template<bool LOGITS>
__global__ __launch_bounds__(256) void gemm64_k(
    const float* __restrict__ A, int lda,
    const float* __restrict__ W, int ldw,
    const float* __restrict__ bias,
    float* __restrict__ C, int ldc, int N, int K,
    const int* __restrict__ declen)
{
  __shared__ float As[32*68];
  __shared__ float Ws[32*68];
  const int tid = threadIdx.x;
  const int m0 = blockIdx.y * 64, n0 = blockIdx.x * 64;
  const int tx = tid & 15, ty = tid >> 4;
  const int r0 = ty * 4, c0 = tx * 4;
  const int lr = tid >> 3, lk = (tid & 7) * 4;
  const float* Ap0 = A + (size_t)(m0 + lr) * lda + lk;
  const float* Ap1 = Ap0 + (size_t)32 * lda;
  bool wg0 = true, wg1 = true;
  if (LOGITS) { wg0 = (n0 + lr) < N; wg1 = (n0 + lr + 32) < N; }
  const float* Wp0 = W + (size_t)(n0 + lr) * ldw + lk;
  const float* Wp1 = W + (size_t)(n0 + lr + 32) * ldw + lk;
  float acc[4][4];
#pragma unroll
  for (int i = 0; i < 4; ++i)
#pragma unroll
    for (int j = 0; j < 4; ++j) acc[i][j] = 0.f;

  for (int k0 = 0; k0 < K; k0 += 32) {
    float4 a0 = *(const float4*)(Ap0 + k0);
    float4 a1 = *(const float4*)(Ap1 + k0);
    float4 w0 = wg0 ? *(const float4*)(Wp0 + k0) : make_float4(0.f,0.f,0.f,0.f);
    float4 w1 = wg1 ? *(const float4*)(Wp1 + k0) : make_float4(0.f,0.f,0.f,0.f);
    __syncthreads();
    As[(lk+0)*68 + lr] = a0.x;  As[(lk+1)*68 + lr] = a0.y;
    As[(lk+2)*68 + lr] = a0.z;  As[(lk+3)*68 + lr] = a0.w;
    As[(lk+0)*68 + lr+32] = a1.x;  As[(lk+1)*68 + lr+32] = a1.y;
    As[(lk+2)*68 + lr+32] = a1.z;  As[(lk+3)*68 + lr+32] = a1.w;
    Ws[(lk+0)*68 + lr] = w0.x;  Ws[(lk+1)*68 + lr] = w0.y;
    Ws[(lk+2)*68 + lr] = w0.z;  Ws[(lk+3)*68 + lr] = w0.w;
    Ws[(lk+0)*68 + lr+32] = w1.x;  Ws[(lk+1)*68 + lr+32] = w1.y;
    Ws[(lk+2)*68 + lr+32] = w1.z;  Ws[(lk+3)*68 + lr+32] = w1.w;
    __syncthreads();
#pragma unroll
    for (int kk = 0; kk < 32; ++kk) {
      float4 a = *(const float4*)&As[kk*68 + r0];
      float4 w = *(const float4*)&Ws[kk*68 + c0];
      const float* ap = (const float*)&a;
      const float* wp = (const float*)&w;
#pragma unroll
      for (int i = 0; i < 4; ++i)
#pragma unroll
        for (int j = 0; j < 4; ++j)
          acc[i][j] = fmaf(ap[i], wp[j], acc[i][j]);
    }
  }
  if (!LOGITS) {
#pragma unroll
    for (int i = 0; i < 4; ++i)
#pragma unroll
      for (int j = 0; j < 4; ++j)
        C[(size_t)(m0 + r0 + i) * ldc + n0 + c0 + j] = acc[i][j] + bias[n0 + c0 + j];
  } else {
#pragma unroll
    for (int i = 0; i < 4; ++i) {
      int rg = m0 + r0 + i;           // rg = t*128 + b
      int tt = rg >> 7, bb = rg & 127;
      bool am = tt < declen[bb];
#pragma unroll
      for (int j = 0; j < 4; ++j) {
        int col = n0 + c0 + j;
        if (col < N) {
          float v = am ? (acc[i][j] + bias[col]) : 0.f;
          C[((size_t)bb * 31 + tt) * 10000 + col] = v;
        }
      }
    }
  }
}

// ---------------------------------------------------------------------------
// Weight concat: Wcat3 (2048x1536) = [W_ih | W_hh]; biasc = b_ih+b_hh;
// Wcat2 (512x1536) = [W_y | W_z | W_h]  (x layout is [emb|gctx|h]).
__global__ __launch_bounds__(256) void k_concat(
    const float* __restrict__ W_ih, const float* __restrict__ W_hh,
    const float* __restrict__ b_ih, const float* __restrict__ b_hh,
    const float* __restrict__ W_y, const float* __restrict__ W_h,
    const float* __restrict__ W_z,
    float* __restrict__ Wcat3, float* __restrict__ biasc, float* __restrict__ Wcat2)
{
  int idx = blockIdx.x * 256 + threadIdx.x;
  int stride = gridDim.x * 256;
  for (int i = idx; i < 2048 * 1536; i += stride) {
    int r = i / 1536, cc = i - r * 1536;
    Wcat3[i] = (cc < 1024) ? W_ih[r * 1024 + cc] : W_hh[r * 512 + cc - 1024];
  }
  for (int i = idx; i < 2048; i += stride) biasc[i] = b_ih[i] + b_hh[i];
  for (int i = idx; i < 512 * 1536; i += stride) {
    int r = i / 1536, cc = i - r * 1536;
    Wcat2[i] = (cc < 512) ? W_y[r * 512 + cc]
             : (cc < 1024 ? W_z[r * 512 + cc - 512] : W_h[r * 512 + cc - 1024]);
  }
}

// mean over L, dec_len (int ws + float out)
__global__ __launch_bounds__(256) void k_mean(
    const float* __restrict__ ann, const int* __restrict__ lengths,
    float* __restrict__ meanb, int* __restrict__ declen, float* __restrict__ out_dec)
{
  int b = blockIdx.x, tid = threadIdx.x;
  const float* ab = ann + (size_t)b * 196 * 512;
  for (int f = tid; f < 512; f += 256) {
    float s = 0.f;
    for (int l = 0; l < 196; ++l) s += ab[l * 512 + f];
    meanb[b * 512 + f] = s * (1.f / 196.f);
  }
  if (tid == 0) {
    int d = lengths[b] - 1;
    if (d < 1) d = 1;
    declen[b] = d;
    out_dec[b] = (float)d;
  }
}

// ---------------------------------------------------------------------------
// Per-step attention: scores = relu(annp + hp) @ wv + bv; softmax; alpha out
// (masked); context; gctx = sigmoid(gatep)*context -> x[:,512:1024];
// emb gather -> x[:,0:512]. One block per batch row.
__global__ __launch_bounds__(256) void k_attn(
    const float* __restrict__ annp, const float* __restrict__ ann,
    const float* __restrict__ hp, const float* __restrict__ gatep,
    const float* __restrict__ wv, const float* __restrict__ bv,
    const int* __restrict__ captions, const float* __restrict__ E_emb,
    const int* __restrict__ declen,
    float* __restrict__ x, float* __restrict__ out_alpha, int t)
{
  int b = blockIdx.x, tid = threadIdx.x;
  int lane = tid & 63, wave = tid >> 6;
  __shared__ float s_hp[512];
  __shared__ float s_sc[196];
  __shared__ float s_red[8];
  s_hp[tid]       = hp[b * 512 + tid];
  s_hp[tid + 256] = hp[b * 512 + 256 + tid];
  __syncthreads();
  const float* ap = annp + (size_t)b * 196 * 512;
  for (int l = wave; l < 196; l += 4) {
    const float* row = ap + l * 512;
    float acc = 0.f;
#pragma unroll
    for (int a0 = 0; a0 < 512; a0 += 64) {
      float v = row[a0 + lane] + s_hp[a0 + lane];
      acc = fmaf(fmaxf(v, 0.f), wv[a0 + lane], acc);
    }
    for (int off = 32; off; off >>= 1) acc += __shfl_xor(acc, off, 64);
    if (lane == 0) s_sc[l] = acc + bv[0];
  }
  __syncthreads();
  float v = (tid < 196) ? s_sc[tid] : -3.402823466e38f;
  float m = v;
  for (int off = 32; off; off >>= 1) m = fmaxf(m, __shfl_xor(m, off, 64));
  if (lane == 0) s_red[wave] = m;
  __syncthreads();
  m = fmaxf(fmaxf(s_red[0], s_red[1]), fmaxf(s_red[2], s_red[3]));
  float e = (tid < 196) ? expf(v - m) : 0.f;
  float s = e;
  for (int off = 32; off; off >>= 1) s += __shfl_xor(s, off, 64);
  if (lane == 0) s_red[4 + wave] = s;
  __syncthreads();
  s = s_red[4] + s_red[5] + s_red[6] + s_red[7];
  float inv = 1.f / s;
  bool active = t < declen[b];
  if (tid < 196) {
    float al = e * inv;
    s_sc[tid] = al;
    out_alpha[((size_t)b * 31 + t) * 196 + tid] = active ? al : 0.f;
  }
  __syncthreads();
  const float* ab = ann + (size_t)b * 196 * 512;
  for (int f = tid; f < 512; f += 256) {
    float ctx = 0.f;
    for (int l = 0; l < 196; ++l) ctx = fmaf(s_sc[l], ab[l * 512 + f], ctx);
    float g = sigmf(gatep[b * 512 + f]);
    x[b * 1536 + 512 + f] = g * ctx;
  }
  int tok = captions[b * 32 + t];
  const float* er = E_emb + (size_t)tok * 512;
  for (int e2 = tid; e2 < 512; e2 += 256) x[b * 1536 + e2] = er[e2];
}

// Gates GEMM, K-split x2 into partials g0/g1 (summed in k_lstm).
__global__ __launch_bounds__(256) void k_gates(
    const float* __restrict__ x, const float* __restrict__ Wc3,
    const float* __restrict__ biasc, float* __restrict__ g0, float* __restrict__ g1)
{
  __shared__ float As[32*36];
  __shared__ float Ws[32*68];
  int blk = blockIdx.x;              // 0..255
  int half = blk >> 7, sub = blk & 127;
  gemm32_body(As, Ws, sub >> 5, sub & 31, x + half * 768, 1536, Wc3 + half * 768, 1536,
              half ? nullptr : biasc, half ? g1 : g0, 2048, 768, 0);
}

// LSTM pointwise: masked h/c update (inactive rows keep old h,c).
__global__ __launch_bounds__(256) void k_lstm(
    const float* __restrict__ g0, const float* __restrict__ g1,
    float* __restrict__ c, float* __restrict__ x,
    const int* __restrict__ declen, int t)
{
  int idx = blockIdx.x * 256 + threadIdx.x;   // 0..65535
  int b = idx >> 9, j = idx & 511;
  if (t >= declen[b]) return;
  int gb = b * 2048 + j;
  float i_ = g0[gb]        + g1[gb];
  float f_ = g0[gb + 512]  + g1[gb + 512];
  float gg = g0[gb + 1024] + g1[gb + 1024];
  float o_ = g0[gb + 1536] + g1[gb + 1536];
  float cn = sigmf(f_) * c[idx] + sigmf(i_) * tanhf(gg);
  float hn = sigmf(o_) * tanhf(cn);
  c[idx] = cn;
  x[b * 1536 + 1024 + j] = hn;
}

// Step tail: pre partials (K-split x2, combined+tanh later) + next-step
// hp / gate-preact GEMMs, merged into one launch. 128 blocks.
__global__ __launch_bounds__(256) void k_tail(
    const float* __restrict__ x, const float* __restrict__ Wcat2,
    const float* __restrict__ W_att_h, const float* __restrict__ b_att_h,
    const float* __restrict__ W_beta, const float* __restrict__ b_beta,
    float* __restrict__ pre0t, float* __restrict__ pre1t,
    float* __restrict__ hp, float* __restrict__ gatep, int do_s5)
{
  __shared__ float As[32*36];
  __shared__ float Ws[32*68];
  int blk = blockIdx.x;
  if (blk < 64) {
    if (!do_s5) return;
    int half = blk >> 5, sub = blk & 31;
    gemm32_body(As, Ws, sub >> 3, sub & 7, x + half * 768, 1536, Wcat2 + half * 768, 1536,
                nullptr, half ? pre1t : pre0t, 512, 768, 0);
  } else if (blk < 96) {
    int sub = blk - 64;
    gemm32_body(As, Ws, sub >> 3, sub & 7, x + 1024, 1536, W_att_h, 512, b_att_h,
                hp, 512, 512, 0);
  } else {
    int sub = blk - 96;
    gemm32_body(As, Ws, sub >> 3, sub & 7, x + 1024, 1536, W_beta, 512, b_beta,
                gatep, 512, 512, 0);
  }
}

__global__ __launch_bounds__(256) void k_combine(
    const float* __restrict__ p0, const float* __restrict__ p1,
    float* __restrict__ pre, int n)
{
  int i = blockIdx.x * 256 + threadIdx.x;
  if (i < n) pre[i] = tanhf(p0[i] + p1[i]);
}

// ---------------------------------------------------------------------------
extern "C" void kernel_launch(void* const* d_in, const int* in_sizes, int n_in,
                              void* d_out, int out_size, void* d_ws, size_t ws_size,
                              hipStream_t stream)
{
  const float* ann      = (const float*)d_in[0];
  const int*   captions = (const int*)d_in[1];
  const int*   lengths  = (const int*)d_in[2];
  const float* E_emb    = (const float*)d_in[3];
  const float* W_init_h = (const float*)d_in[4];
  const float* b_init_h = (const float*)d_in[5];
  const float* W_init_c = (const float*)d_in[6];
  const float* b_init_c = (const float*)d_in[7];
  const float* W_att_f  = (const float*)d_in[8];
  const float* b_att_f  = (const float*)d_in[9];
  const float* W_att_h  = (const float*)d_in[10];
  const float* b_att_h  = (const float*)d_in[11];
  const float* w_att_v  = (const float*)d_in[12];
  const float* b_att_v  = (const float*)d_in[13];
  const float* W_beta   = (const float*)d_in[14];
  const float* b_beta   = (const float*)d_in[15];
  const float* W_ih     = (const float*)d_in[16];
  const float* W_hh     = (const float*)d_in[17];
  const float* b_ih     = (const float*)d_in[18];
  const float* b_hh     = (const float*)d_in[19];
  const float* W_y      = (const float*)d_in[20];
  const float* W_h      = (const float*)d_in[21];
  const float* W_z      = (const float*)d_in[22];
  const float* W_out    = (const float*)d_in[23];
  const float* b_out    = (const float*)d_in[24];

  float* out        = (float*)d_out;
  float* out_logits = out;                       // 128*31*10000
  float* out_alpha  = out + 39680000ll;          // 128*31*196
  float* out_dec    = out + 40457728ll;          // 128

  float* ws    = (float*)d_ws;
  float* Wcat3 = ws;                      // 2048*1536
  float* biasc = Wcat3 + 3145728;         // 2048
  float* Wcat2 = biasc + 2048;            // 512*1536
  float* annp  = Wcat2 + 786432;          // 128*196*512
  float* pre0  = annp  + 12845056;        // 31*128*512
  float* pre1  = pre0  + 2031616;
  float* preA  = pre1  + 2031616;
  float* x     = preA  + 2031616;         // 128*1536  [emb|gctx|h]
  float* hpb   = x     + 196608;          // 128*512
  float* gatep = hpb   + 65536;           // 128*512 (pre-sigmoid)
  float* g0    = gatep + 65536;           // 128*2048
  float* g1    = g0    + 262144;
  float* cbuf  = g1    + 262144;          // 128*512
  float* meanb = cbuf  + 65536;           // 128*512
  int*   declen = (int*)(meanb + 65536);  // 128

  // ---- phase 1: weights, mean, h0/c0, ann_proj, initial hp/gate ----
  hipLaunchKernelGGL(k_concat, dim3(4096), dim3(256), 0, stream,
                     W_ih, W_hh, b_ih, b_hh, W_y, W_h, W_z, Wcat3, biasc, Wcat2);
  hipLaunchKernelGGL(k_mean, dim3(128), dim3(256), 0, stream,
                     ann, lengths, meanb, declen, out_dec);
  hipLaunchKernelGGL(gemm32_k, dim3(8, 4), dim3(256), 0, stream,
                     meanb, 512, W_init_h, 512, b_init_h, x + 1024, 1536, 512, 2);
  hipLaunchKernelGGL(gemm32_k, dim3(8, 4), dim3(256), 0, stream,
                     meanb, 512, W_init_c, 512, b_init_c, cbuf, 512, 512, 2);
  hipLaunchKernelGGL(gemm64_k<false>, dim3(8, 392), dim3(256), 0, stream,
                     ann, 512, W_att_f, 512, b_att_f, annp, 512, 512, 512,
                     (const int*)nullptr);
  hipLaunchKernelGGL(k_tail, dim3(128), dim3(256), 0, stream,
                     x, Wcat2, W_att_h, b_att_h, W_beta, b_beta,
                     pre0, pre1, hpb, gatep, 0);

  // ---- phase 2: 31 sequential decode steps ----
  for (int t = 0; t < 31; ++t) {
    hipLaunchKernelGGL(k_attn, dim3(128), dim3(256), 0, stream,
                       annp, ann, hpb, gatep, w_att_v, b_att_v, captions, E_emb,
                       declen, x, out_alpha, t);
    hipLaunchKernelGGL(k_gates, dim3(256), dim3(256), 0, stream,
                       x, Wcat3, biasc, g0, g1);
    hipLaunchKernelGGL(k_lstm, dim3(256), dim3(256), 0, stream,
                       g0, g1, cbuf, x, declen, t);
    hipLaunchKernelGGL(k_tail, dim3(128), dim3(256), 0, stream,
                       x, Wcat2, W_att_h, b_att_h, W_beta, b_beta,
                       pre0 + t * 65536, pre1 + t * 65536, hpb, gatep, 1);
  }

  // ---- phase 3: pre = tanh(pre0+pre1); logits = pre @ W_out^T + b_out ----
  hipLaunchKernelGGL(k_combine, dim3(7936), dim3(256), 0, stream,
                     pre0, pre1, preA, 2031616);
  hipLaunchKernelGGL(gemm64_k<true>, dim3(157, 62), dim3(256), 0, stream,
                     preA, 512, W_out, 512, b_out, out_logits, 10000, 10000, 512,
                     declen);
}

// Round 2
// 3541.969 us; speedup vs baseline: 1.2343x; 1.2343x over previous
//
#include <hip/hip_runtime.h>
#include <cstdint>

// AttentionDecoder: B=128, L=196, T_dec=31, E=H=F=A=512, V=10000
// Out: logits (128*31*10000) | alphas (128*31*196) | dec_len (128), fp32.

#define DEV __device__ __forceinline__

typedef __bf16 bf16x8 __attribute__((ext_vector_type(8)));
typedef float  f32x4  __attribute__((ext_vector_type(4)));

DEV float sigmf(float v) { return 1.f / (1.f + expf(-v)); }

DEV ushort f2bf(float f) {
  union { float f; uint32_t u; } c; c.f = f;
  uint32_t u = c.u;
  return (ushort)((u + 0x7FFFu + ((u >> 16) & 1u)) >> 16);
}
DEV float bf2f(ushort h) {
  union { uint32_t u; float f; } c; c.u = ((uint32_t)h) << 16;
  return c.f;
}
DEV void cvt8(const float* __restrict__ s, ushort* __restrict__ d) {
  float4 a = *(const float4*)s;
  float4 b = *(const float4*)(s + 4);
  ushort4 lo = make_ushort4(f2bf(a.x), f2bf(a.y), f2bf(a.z), f2bf(a.w));
  ushort4 hi = make_ushort4(f2bf(b.x), f2bf(b.y), f2bf(b.z), f2bf(b.w));
  *(ushort4*)d = lo;
  *(ushort4*)(d + 4) = hi;
}

// ---------------------------------------------------------------------------
// 128x128-tile bf16 MFMA GEMM: C = A(MxK) @ W(NxK)^T. 256 thr = 4 waves,
// wave = 64x64 via 4x4 frags of v_mfma_f32_16x16x32_bf16. BK=64.
// LDS tiles row-major [128][72] ushort (+8 pad, 16B-aligned rows).
// A frag: lane reads A[m=lane&15][k=(lane>>4)*8 ..+8]; same for W (B^T).
// C/D: col=lane&15, row=(lane>>4)*4+reg  [m89-verified].
// mode 0: fp32 out + bias; 1: bf16 out; 2: bf16 out tanh;
// mode 3: logits remap row=t*128+b -> Cf[b][t][col], mask t<declen[b], col<Ncols.
DEV void mfma_body(ushort* As, ushort* Ws, int mt, int nt,
                   const ushort* __restrict__ A, int lda,
                   const ushort* __restrict__ W, int ldw,
                   int K, int mode, const float* __restrict__ bias,
                   float* __restrict__ Cf, ushort* __restrict__ Cb, int ldc,
                   int Ncols, const int* __restrict__ declen)
{
  const int tid = threadIdx.x;
  const int m0 = mt * 128, n0 = nt * 128;
  const int wv = tid >> 6, lane = tid & 63;
  const int rw = (wv & 1) * 64, cw = (wv >> 1) * 64;
  const int lrow = lane & 15, lk = (lane >> 4) * 8;
  f32x4 acc[4][4];
#pragma unroll
  for (int i = 0; i < 4; ++i)
#pragma unroll
    for (int j = 0; j < 4; ++j) acc[i][j] = (f32x4){0.f, 0.f, 0.f, 0.f};

  const int srow = tid >> 3;
  const int sc8  = tid & 7;
  for (int k0 = 0; k0 < K; k0 += 64) {
    __syncthreads();
#pragma unroll
    for (int it = 0; it < 4; ++it) {
      int row = it * 32 + srow;
      *(uint4*)&As[row * 72 + sc8 * 8] =
          *(const uint4*)&A[(size_t)(m0 + row) * lda + k0 + sc8 * 8];
      *(uint4*)&Ws[row * 72 + sc8 * 8] =
          *(const uint4*)&W[(size_t)(n0 + row) * ldw + k0 + sc8 * 8];
    }
    __syncthreads();
#pragma unroll
    for (int ks = 0; ks < 64; ks += 32) {
      bf16x8 af[4], bfr[4];
#pragma unroll
      for (int i = 0; i < 4; ++i)
        af[i] = *(const bf16x8*)&As[(rw + i * 16 + lrow) * 72 + ks + lk];
#pragma unroll
      for (int j = 0; j < 4; ++j)
        bfr[j] = *(const bf16x8*)&Ws[(cw + j * 16 + lrow) * 72 + ks + lk];
#pragma unroll
      for (int i = 0; i < 4; ++i)
#pragma unroll
        for (int j = 0; j < 4; ++j)
          acc[i][j] = __builtin_amdgcn_mfma_f32_16x16x32_bf16(af[i], bfr[j],
                                                              acc[i][j], 0, 0, 0);
    }
  }
  const int rsub = (lane >> 4) * 4;
#pragma unroll
  for (int i = 0; i < 4; ++i) {
#pragma unroll
    for (int j = 0; j < 4; ++j) {
      int col = n0 + cw + j * 16 + lrow;
#pragma unroll
      for (int r = 0; r < 4; ++r) {
        int row = m0 + rw + i * 16 + rsub + r;
        float v = acc[i][j][r];
        if (mode == 0) {
          Cf[(size_t)row * ldc + col] = v + bias[col];
        } else if (mode == 1) {
          Cb[(size_t)row * ldc + col] = f2bf(v);
        } else if (mode == 2) {
          Cb[(size_t)row * ldc + col] = f2bf(tanhf(v));
        } else {
          int tt = row >> 7, bb = row & 127;
          if (col < Ncols) {
            float o = (tt < declen[bb]) ? v + bias[col] : 0.f;
            Cf[((size_t)bb * 31 + tt) * 10000 + col] = o;
          }
        }
      }
    }
  }
}

__global__ __launch_bounds__(256) void k_mfma(
    const ushort* __restrict__ A, int lda, const ushort* __restrict__ W, int ldw,
    int K, int mode, const float* __restrict__ bias,
    float* __restrict__ Cf, ushort* __restrict__ Cb, int ldc, int Ncols,
    const int* __restrict__ declen)
{
  __shared__ ushort As[128 * 72];
  __shared__ ushort Ws[128 * 72];
  mfma_body(As, Ws, blockIdx.y, blockIdx.x, A, lda, W, ldw, K, mode, bias,
            Cf, Cb, ldc, Ncols, declen);
}

// Tail: blk 0-3 pre (tanh->bf16), 4-7 hp (bias=b_att_h+b_att_f), 8-11 gatep.
__global__ __launch_bounds__(256) void k_tailm(
    const ushort* __restrict__ x_bf, const ushort* __restrict__ Wcat2_bf,
    const ushort* __restrict__ Wah_bf, const ushort* __restrict__ Wb_bf,
    const float* __restrict__ b_hf, const float* __restrict__ b_beta,
    ushort* __restrict__ preA_t, float* __restrict__ hpb,
    float* __restrict__ gatep, int blk0)
{
  __shared__ ushort As[128 * 72];
  __shared__ ushort Ws[128 * 72];
  int blk = blockIdx.x + blk0;
  if (blk < 4)
    mfma_body(As, Ws, 0, blk, x_bf, 1536, Wcat2_bf, 1536, 1536, 2, nullptr,
              nullptr, preA_t, 512, 512, nullptr);
  else if (blk < 8)
    mfma_body(As, Ws, 0, blk - 4, x_bf + 1024, 1536, Wah_bf, 512, 512, 0, b_hf,
              hpb, nullptr, 512, 512, nullptr);
  else
    mfma_body(As, Ws, 0, blk - 8, x_bf + 1024, 1536, Wb_bf, 512, 512, 0, b_beta,
              gatep, nullptr, 512, 512, nullptr);
}

// ---------------------------------------------------------------------------
// Prep: weight concats/conversions to bf16 + bias sums. Grid-stride.
__global__ __launch_bounds__(256) void k_prep(
    const float* __restrict__ W_ih, const float* __restrict__ W_hh,
    const float* __restrict__ b_ih, const float* __restrict__ b_hh,
    const float* __restrict__ W_y, const float* __restrict__ W_h,
    const float* __restrict__ W_z, const float* __restrict__ W_out,
    const float* __restrict__ W_att_f, const float* __restrict__ W_att_h,
    const float* __restrict__ W_beta, const float* __restrict__ b_att_f,
    const float* __restrict__ b_att_h, const float* __restrict__ ann,
    ushort* __restrict__ Wcat3_bf, ushort* __restrict__ Wcat2_bf,
    ushort* __restrict__ Wo_bf, ushort* __restrict__ Waf_bf,
    ushort* __restrict__ Wah_bf, ushort* __restrict__ Wb_bf,
    ushort* __restrict__ ann_bf, float* __restrict__ biasc,
    float* __restrict__ b_hf)
{
  int idx = blockIdx.x * 256 + threadIdx.x;
  int stride = gridDim.x * 256;
  for (int i = idx; i < 12845056 / 8; i += stride)
    cvt8(ann + (size_t)i * 8, ann_bf + (size_t)i * 8);
  for (int i = idx; i < 3145728 / 8; i += stride) {
    int k8 = i * 8, r = k8 / 1536, c = k8 - r * 1536;
    const float* src = (c < 1024) ? (W_ih + (size_t)r * 1024 + c)
                                  : (W_hh + (size_t)r * 512 + c - 1024);
    cvt8(src, Wcat3_bf + k8);
  }
  for (int i = idx; i < 786432 / 8; i += stride) {
    int k8 = i * 8, r = k8 / 1536, c = k8 - r * 1536;
    const float* src = (c < 512) ? (W_y + (size_t)r * 512 + c)
                     : (c < 1024 ? (W_z + (size_t)r * 512 + c - 512)
                                 : (W_h + (size_t)r * 512 + c - 1024));
    cvt8(src, Wcat2_bf + k8);
  }
  for (int i = idx; i < 5177344 / 8; i += stride) {   // Wo: 10112x512, pad 0
    int r = i >> 6, c8 = i & 63;
    if (r < 10000) cvt8(W_out + (size_t)r * 512 + c8 * 8, Wo_bf + (size_t)i * 8);
    else { *(uint4*)(Wo_bf + (size_t)i * 8) = make_uint4(0, 0, 0, 0); }
  }
  for (int i = idx; i < 262144 / 8; i += stride) {
    cvt8(W_att_f + i * 8, Waf_bf + i * 8);
    cvt8(W_att_h + i * 8, Wah_bf + i * 8);
    cvt8(W_beta + i * 8, Wb_bf + i * 8);
  }
  for (int i = idx; i < 2048; i += stride) biasc[i] = b_ih[i] + b_hh[i];
  for (int i = idx; i < 512; i += stride) b_hf[i] = b_att_h[i] + b_att_f[i];
}

// mean over L, dec_len
__global__ __launch_bounds__(256) void k_mean(
    const float* __restrict__ ann, const int* __restrict__ lengths,
    float* __restrict__ meanb, int* __restrict__ declen, float* __restrict__ out_dec)
{
  int b = blockIdx.x, tid = threadIdx.x;
  const float* ab = ann + (size_t)b * 196 * 512;
  for (int f = tid; f < 512; f += 256) {
    float s = 0.f;
    for (int l = 0; l < 196; ++l) s += ab[l * 512 + f];
    meanb[b * 512 + f] = s * (1.f / 196.f);
  }
  if (tid == 0) {
    int d = lengths[b] - 1;
    if (d < 1) d = 1;
    declen[b] = d;
    out_dec[b] = (float)d;
  }
}

// fp32 32x64-tile GEMM for h0/c0 init (tiny).
DEV float actf(float v, int act) { return act == 2 ? tanhf(v) : v; }
__global__ __launch_bounds__(256) void gemm32_k(
    const float* __restrict__ A, int lda, const float* __restrict__ W, int ldw,
    const float* __restrict__ bias, float* __restrict__ C, int ldc, int K, int act)
{
  __shared__ float As[32 * 36];
  __shared__ float Ws[32 * 68];
  const int tid = threadIdx.x;
  const int m0 = blockIdx.y * 32, n0 = blockIdx.x * 64;
  const int tx = tid & 15, ty = tid >> 4;
  const int r0 = ty * 2, c0 = tx * 4;
  const int lr = tid >> 3, lk = (tid & 7) * 4;
  const float* Ap = A + (size_t)(m0 + lr) * lda + lk;
  const float* Wp0 = W + (size_t)(n0 + lr) * ldw + lk;
  const float* Wp1 = W + (size_t)(n0 + lr + 32) * ldw + lk;
  float acc[2][4] = {{0.f, 0.f, 0.f, 0.f}, {0.f, 0.f, 0.f, 0.f}};
  for (int k0 = 0; k0 < K; k0 += 32) {
    float4 av = *(const float4*)(Ap + k0);
    float4 w0 = *(const float4*)(Wp0 + k0);
    float4 w1 = *(const float4*)(Wp1 + k0);
    __syncthreads();
    As[(lk + 0) * 36 + lr] = av.x; As[(lk + 1) * 36 + lr] = av.y;
    As[(lk + 2) * 36 + lr] = av.z; As[(lk + 3) * 36 + lr] = av.w;
    Ws[(lk + 0) * 68 + lr] = w0.x; Ws[(lk + 1) * 68 + lr] = w0.y;
    Ws[(lk + 2) * 68 + lr] = w0.z; Ws[(lk + 3) * 68 + lr] = w0.w;
    Ws[(lk + 0) * 68 + lr + 32] = w1.x; Ws[(lk + 1) * 68 + lr + 32] = w1.y;
    Ws[(lk + 2) * 68 + lr + 32] = w1.z; Ws[(lk + 3) * 68 + lr + 32] = w1.w;
    __syncthreads();
#pragma unroll
    for (int kk = 0; kk < 32; ++kk) {
      float2 a = *(const float2*)&As[kk * 36 + r0];
      float4 w = *(const float4*)&Ws[kk * 68 + c0];
      const float aa[2] = {a.x, a.y};
      const float* wwp = (const float*)&w;
#pragma unroll
      for (int i = 0; i < 2; ++i)
#pragma unroll
        for (int j = 0; j < 4; ++j)
          acc[i][j] = fmaf(aa[i], wwp[j], acc[i][j]);
    }
  }
#pragma unroll
  for (int i = 0; i < 2; ++i)
#pragma unroll
    for (int j = 0; j < 4; ++j)
      C[(size_t)(m0 + r0 + i) * ldc + n0 + c0 + j] =
          actf(acc[i][j] + bias[n0 + c0 + j], act);
}

__global__ __launch_bounds__(256) void k_cvt_h0(
    const float* __restrict__ h0f, ushort* __restrict__ x_bf)
{
  int idx = blockIdx.x * 256 + threadIdx.x;   // 65536
  int b = idx >> 9, j = idx & 511;
  x_bf[b * 1536 + 1024 + j] = f2bf(h0f[idx]);
}

// ---------------------------------------------------------------------------
// Attention step.
__global__ __launch_bounds__(512) void k_attn(
    const ushort* __restrict__ annp_bf, const ushort* __restrict__ ann_bf,
    const float* __restrict__ hp, const float* __restrict__ gatep,
    const float* __restrict__ wv, const float* __restrict__ bv,
    const int* __restrict__ captions, const float* __restrict__ E_emb,
    const int* __restrict__ declen,
    ushort* __restrict__ x_bf, float* __restrict__ out_alpha, int t)
{
  int b = blockIdx.x, tid = threadIdx.x;
  int lane = tid & 63, wvx = tid >> 6;   // 8 waves
  __shared__ float s_hp[512];
  __shared__ float s_wv[512];
  __shared__ float s_sc[196];
  __shared__ float s_red[16];
  s_hp[tid] = hp[b * 512 + tid];
  s_wv[tid] = wv[tid];
  __syncthreads();
  const ushort* ap = annp_bf + (size_t)b * 196 * 512;
  for (int l = wvx; l < 196; l += 8) {
    const ushort* row = ap + l * 512;
    float acc = 0.f;
#pragma unroll
    for (int a0 = 0; a0 < 512; a0 += 256) {
      ushort4 rv = *(const ushort4*)(row + a0 + lane * 4);
      float4 hv = *(const float4*)&s_hp[a0 + lane * 4];
      float4 wt = *(const float4*)&s_wv[a0 + lane * 4];
      float v0 = bf2f(rv.x) + hv.x, v1 = bf2f(rv.y) + hv.y;
      float v2 = bf2f(rv.z) + hv.z, v3 = bf2f(rv.w) + hv.w;
      acc = fmaf(fmaxf(v0, 0.f), wt.x, acc);
      acc = fmaf(fmaxf(v1, 0.f), wt.y, acc);
      acc = fmaf(fmaxf(v2, 0.f), wt.z, acc);
      acc = fmaf(fmaxf(v3, 0.f), wt.w, acc);
    }
    for (int off = 32; off; off >>= 1) acc += __shfl_xor(acc, off, 64);
    if (lane == 0) s_sc[l] = acc + bv[0];
  }
  __syncthreads();
  float v = (tid < 196) ? s_sc[tid] : -3.402823466e38f;
  float m = v;
  for (int off = 32; off; off >>= 1) m = fmaxf(m, __shfl_xor(m, off, 64));
  if (lane == 0) s_red[wvx] = m;
  __syncthreads();
  m = s_red[0];
#pragma unroll
  for (int i = 1; i < 8; ++i) m = fmaxf(m, s_red[i]);
  float e = (tid < 196) ? expf(v - m) : 0.f;
  float s = e;
  for (int off = 32; off; off >>= 1) s += __shfl_xor(s, off, 64);
  if (lane == 0) s_red[8 + wvx] = s;
  __syncthreads();
  s = 0.f;
#pragma unroll
  for (int i = 0; i < 8; ++i) s += s_red[8 + i];
  float inv = 1.f / s;
  bool active = t < declen[b];
  if (tid < 196)
    out_alpha[((size_t)b * 31 + t) * 196 + tid] = active ? e * inv : 0.f;
  __syncthreads();
  if (tid < 196) s_sc[tid] = e * inv;
  __syncthreads();
  const ushort* ab = ann_bf + (size_t)b * 196 * 512;
  float ctx = 0.f;
  for (int l = 0; l < 196; ++l) ctx = fmaf(s_sc[l], bf2f(ab[l * 512 + tid]), ctx);
  float g = sigmf(gatep[b * 512 + tid]);
  x_bf[b * 1536 + 512 + tid] = f2bf(g * ctx);
  int tok = captions[b * 32 + t];
  x_bf[b * 1536 + tid] = f2bf(E_emb[(size_t)tok * 512 + tid]);
}

// LSTM pointwise: masked h/c update; h -> bf16 into x_bf.
__global__ __launch_bounds__(256) void k_lstm(
    const float* __restrict__ gates, float* __restrict__ c,
    ushort* __restrict__ x_bf, const int* __restrict__ declen, int t)
{
  int idx = blockIdx.x * 256 + threadIdx.x;   // 65536
  int b = idx >> 9, j = idx & 511;
  if (t >= declen[b]) return;
  const float* gb = gates + (size_t)b * 2048 + j;
  float i_ = gb[0], f_ = gb[512], gg = gb[1024], o_ = gb[1536];
  float cn = sigmf(f_) * c[idx] + sigmf(i_) * tanhf(gg);
  float hn = sigmf(o_) * tanhf(cn);
  c[idx] = cn;
  x_bf[b * 1536 + 1024 + j] = f2bf(hn);
}

// ---------------------------------------------------------------------------
extern "C" void kernel_launch(void* const* d_in, const int* in_sizes, int n_in,
                              void* d_out, int out_size, void* d_ws, size_t ws_size,
                              hipStream_t stream)
{
  const float* ann      = (const float*)d_in[0];
  const int*   captions = (const int*)d_in[1];
  const int*   lengths  = (const int*)d_in[2];
  const float* E_emb    = (const float*)d_in[3];
  const float* W_init_h = (const float*)d_in[4];
  const float* b_init_h = (const float*)d_in[5];
  const float* W_init_c = (const float*)d_in[6];
  const float* b_init_c = (const float*)d_in[7];
  const float* W_att_f  = (const float*)d_in[8];
  const float* b_att_f  = (const float*)d_in[9];
  const float* W_att_h  = (const float*)d_in[10];
  const float* b_att_h  = (const float*)d_in[11];
  const float* w_att_v  = (const float*)d_in[12];
  const float* b_att_v  = (const float*)d_in[13];
  const float* W_beta   = (const float*)d_in[14];
  const float* b_beta   = (const float*)d_in[15];
  const float* W_ih     = (const float*)d_in[16];
  const float* W_hh     = (const float*)d_in[17];
  const float* b_ih     = (const float*)d_in[18];
  const float* b_hh     = (const float*)d_in[19];
  const float* W_y      = (const float*)d_in[20];
  const float* W_h      = (const float*)d_in[21];
  const float* W_z      = (const float*)d_in[22];
  const float* W_out    = (const float*)d_in[23];
  const float* b_out    = (const float*)d_in[24];

  float* out        = (float*)d_out;
  float* out_logits = out;
  float* out_alpha  = out + 39680000ll;
  float* out_dec    = out + 40457728ll;

  char* p = (char*)d_ws;
  auto alloc_us = [&](size_t n) { ushort* r = (ushort*)p; p += ((n * 2 + 255) & ~(size_t)255); return r; };
  auto alloc_f  = [&](size_t n) { float*  r = (float*)p;  p += ((n * 4 + 255) & ~(size_t)255); return r; };
  ushort* Wo_bf    = alloc_us(10112 * 512);
  ushort* Wcat3_bf = alloc_us(2048 * 1536);
  ushort* Wcat2_bf = alloc_us(512 * 1536);
  ushort* Waf_bf   = alloc_us(512 * 512);
  ushort* Wah_bf   = alloc_us(512 * 512);
  ushort* Wb_bf    = alloc_us(512 * 512);
  ushort* ann_bf   = alloc_us(12845056);
  ushort* annp_bf  = alloc_us(12845056);
  ushort* preA_bf  = alloc_us(3968 * 512);
  ushort* x_bf     = alloc_us(128 * 1536);
  float* biasc = alloc_f(2048);
  float* b_hf  = alloc_f(512);
  float* hpb   = alloc_f(65536);
  float* gatep = alloc_f(65536);
  float* gates = alloc_f(262144);
  float* cbuf  = alloc_f(65536);
  float* meanb = alloc_f(65536);
  float* h0f   = alloc_f(65536);
  int*   declen = (int*)alloc_f(128);

  // ---- phase 1 ----
  hipLaunchKernelGGL(k_prep, dim3(1024), dim3(256), 0, stream,
                     W_ih, W_hh, b_ih, b_hh, W_y, W_h, W_z, W_out,
                     W_att_f, W_att_h, W_beta, b_att_f, b_att_h, ann,
                     Wcat3_bf, Wcat2_bf, Wo_bf, Waf_bf, Wah_bf, Wb_bf, ann_bf,
                     biasc, b_hf);
  hipLaunchKernelGGL(k_mean, dim3(128), dim3(256), 0, stream,
                     ann, lengths, meanb, declen, out_dec);
  hipLaunchKernelGGL(gemm32_k, dim3(8, 4), dim3(256), 0, stream,
                     meanb, 512, W_init_h, 512, b_init_h, h0f, 512, 512, 2);
  hipLaunchKernelGGL(gemm32_k, dim3(8, 4), dim3(256), 0, stream,
                     meanb, 512, W_init_c, 512, b_init_c, cbuf, 512, 512, 2);
  hipLaunchKernelGGL(k_cvt_h0, dim3(256), dim3(256), 0, stream, h0f, x_bf);
  hipLaunchKernelGGL(k_mfma, dim3(4, 196), dim3(256), 0, stream,
                     ann_bf, 512, Waf_bf, 512, 512, 1, (const float*)nullptr,
                     (float*)nullptr, annp_bf, 512, 512, (const int*)nullptr);
  hipLaunchKernelGGL(k_tailm, dim3(8), dim3(256), 0, stream,
                     x_bf, Wcat2_bf, Wah_bf, Wb_bf, b_hf, b_beta,
                     preA_bf, hpb, gatep, 4);

  // ---- phase 2: 31 steps ----
  for (int t = 0; t < 31; ++t) {
    hipLaunchKernelGGL(k_attn, dim3(128), dim3(512), 0, stream,
                       annp_bf, ann_bf, hpb, gatep, w_att_v, b_att_v,
                       captions, E_emb, declen, x_bf, out_alpha, t);
    hipLaunchKernelGGL(k_mfma, dim3(16, 1), dim3(256), 0, stream,
                       x_bf, 1536, Wcat3_bf, 1536, 1536, 0, biasc,
                       gates, (ushort*)nullptr, 2048, 2048, (const int*)nullptr);
    hipLaunchKernelGGL(k_lstm, dim3(256), dim3(256), 0, stream,
                       gates, cbuf, x_bf, declen, t);
    hipLaunchKernelGGL(k_tailm, dim3(12), dim3(256), 0, stream,
                       x_bf, Wcat2_bf, Wah_bf, Wb_bf, b_hf, b_beta,
                       preA_bf + (size_t)t * 65536, hpb, gatep, 0);
  }

  // ---- phase 3: logits ----
  hipLaunchKernelGGL(k_mfma, dim3(79, 31), dim3(256), 0, stream,
                     preA_bf, 512, Wo_bf, 512, 512, 3, b_out,
                     out_logits, (ushort*)nullptr, 10000, 10000, declen);
}

// Round 3
// 1741.855 us; speedup vs baseline: 2.5099x; 2.0334x over previous
//
#include <hip/hip_runtime.h>
#include <cstdint>

// AttentionDecoder: B=128, L=196, T_dec=31, E=H=F=A=512, V=10000
// Out: logits (128*31*10000) | alphas (128*31*196) | dec_len (128), fp32.

#define DEV __device__ __forceinline__

typedef __bf16 bf16x8 __attribute__((ext_vector_type(8)));
typedef float  f32x4  __attribute__((ext_vector_type(4)));

DEV float sigmf(float v) { return 1.f / (1.f + expf(-v)); }

DEV ushort f2bf(float f) {
  union { float f; uint32_t u; } c; c.f = f;
  uint32_t u = c.u;
  return (ushort)((u + 0x7FFFu + ((u >> 16) & 1u)) >> 16);
}
DEV float bf2f(ushort h) {
  union { uint32_t u; float f; } c; c.u = ((uint32_t)h) << 16;
  return c.f;
}
DEV void cvt8(const float* __restrict__ s, ushort* __restrict__ d) {
  float4 a = *(const float4*)s;
  float4 b = *(const float4*)(s + 4);
  ushort4 lo = make_ushort4(f2bf(a.x), f2bf(a.y), f2bf(a.z), f2bf(a.w));
  ushort4 hi = make_ushort4(f2bf(b.x), f2bf(b.y), f2bf(b.z), f2bf(b.w));
  *(ushort4*)d = lo;
  *(ushort4*)(d + 4) = hi;
}

// ---------------------------------------------------------------------------
// 128x128-tile bf16 MFMA GEMM: C = A(128xK) @ W(NxK)^T tile. 256 thr = 4 waves.
// mode 0: fp32 out (+bias if non-null); 1: bf16 out;
// mode 3: logits remap row=t*128+b -> Cf[b][t][col], mask t<declen[b], col<Ncols.
DEV void mfma_body(ushort* As, ushort* Ws, int mt, int nt,
                   const ushort* __restrict__ A, int lda,
                   const ushort* __restrict__ W, int ldw,
                   int K, int mode, const float* __restrict__ bias,
                   float* __restrict__ Cf, ushort* __restrict__ Cb, int ldc,
                   int Ncols, const int* __restrict__ declen)
{
  const int tid = threadIdx.x;
  const int m0 = mt * 128, n0 = nt * 128;
  const int wv = tid >> 6, lane = tid & 63;
  const int rw = (wv & 1) * 64, cw = (wv >> 1) * 64;
  const int lrow = lane & 15, lk = (lane >> 4) * 8;
  f32x4 acc[4][4];
#pragma unroll
  for (int i = 0; i < 4; ++i)
#pragma unroll
    for (int j = 0; j < 4; ++j) acc[i][j] = (f32x4){0.f, 0.f, 0.f, 0.f};

  const int srow = tid >> 3;
  const int sc8  = tid & 7;
  for (int k0 = 0; k0 < K; k0 += 64) {
    __syncthreads();
#pragma unroll
    for (int it = 0; it < 4; ++it) {
      int row = it * 32 + srow;
      *(uint4*)&As[row * 72 + sc8 * 8] =
          *(const uint4*)&A[(size_t)(m0 + row) * lda + k0 + sc8 * 8];
      *(uint4*)&Ws[row * 72 + sc8 * 8] =
          *(const uint4*)&W[(size_t)(n0 + row) * ldw + k0 + sc8 * 8];
    }
    __syncthreads();
#pragma unroll
    for (int ks = 0; ks < 64; ks += 32) {
      bf16x8 af[4], bfr[4];
#pragma unroll
      for (int i = 0; i < 4; ++i)
        af[i] = *(const bf16x8*)&As[(rw + i * 16 + lrow) * 72 + ks + lk];
#pragma unroll
      for (int j = 0; j < 4; ++j)
        bfr[j] = *(const bf16x8*)&Ws[(cw + j * 16 + lrow) * 72 + ks + lk];
#pragma unroll
      for (int i = 0; i < 4; ++i)
#pragma unroll
        for (int j = 0; j < 4; ++j)
          acc[i][j] = __builtin_amdgcn_mfma_f32_16x16x32_bf16(af[i], bfr[j],
                                                              acc[i][j], 0, 0, 0);
    }
  }
  const int rsub = (lane >> 4) * 4;
#pragma unroll
  for (int i = 0; i < 4; ++i) {
#pragma unroll
    for (int j = 0; j < 4; ++j) {
      int col = n0 + cw + j * 16 + lrow;
#pragma unroll
      for (int r = 0; r < 4; ++r) {
        int row = m0 + rw + i * 16 + rsub + r;
        float v = acc[i][j][r];
        if (mode == 0) {
          Cf[(size_t)row * ldc + col] = bias ? v + bias[col] : v;
        } else if (mode == 1) {
          Cb[(size_t)row * ldc + col] = f2bf(v);
        } else {
          int tt = row >> 7, bb = row & 127;
          if (col < Ncols) {
            float o = (tt < declen[bb]) ? v + bias[col] : 0.f;
            Cf[((size_t)bb * 31 + tt) * 10000 + col] = o;
          }
        }
      }
    }
  }
}

// generic (used for annp)
__global__ __launch_bounds__(256) void k_mfma(
    const ushort* __restrict__ A, int lda, const ushort* __restrict__ W, int ldw,
    int K, int mode, const float* __restrict__ bias,
    float* __restrict__ Cf, ushort* __restrict__ Cb, int ldc, int Ncols,
    const int* __restrict__ declen)
{
  __shared__ ushort As[128 * 72];
  __shared__ ushort Ws[128 * 72];
  mfma_body(As, Ws, blockIdx.y, blockIdx.x, A, lda, W, ldw, K, mode, bias,
            Cf, Cb, ldc, Ncols, declen);
}

// Logits with XCD swizzle: same col-tile stays on one XCD across row-tiles.
__global__ __launch_bounds__(256) void k_logits(
    const ushort* __restrict__ preA, const ushort* __restrict__ Wo,
    const float* __restrict__ b_out, float* __restrict__ out_logits,
    const int* __restrict__ declen)
{
  __shared__ ushort As[128 * 72];
  __shared__ ushort Ws[128 * 72];
  int id = blockIdx.x;
  int x = id & 7, g = id >> 3;
  int G = g / 31, row = g - G * 31;
  int col = G * 8 + x;
  if (col >= 79) return;
  mfma_body(As, Ws, row, col, preA, 512, Wo, 512, 512, 3, b_out,
            out_logits, nullptr, 10000, 10000, declen);
}

// Gates split-K: 64 blocks = 16 N-tiles x 4 K-splits (K=384). fp32 partials.
__global__ __launch_bounds__(256) void k_gates(
    const ushort* __restrict__ x_bf, const ushort* __restrict__ Wg,
    float* __restrict__ gP)
{
  __shared__ ushort As[128 * 72];
  __shared__ ushort Ws[128 * 72];
  int nt = blockIdx.x & 15, ks = blockIdx.x >> 4;
  mfma_body(As, Ws, 0, nt, x_bf + ks * 384, 1536, Wg + ks * 384, 1536, 384, 0,
            nullptr, gP + (size_t)ks * 262144, nullptr, 2048, 2048, nullptr);
}

// Tail split-K. normal grid 32: bid 0-15 pre (nt&3, ks>>2, K=384);
// 16-23 hp (ks in {0,1}, K=256); 24-31 gp. init grid 16: 0-7 hp, 8-15 gp.
__global__ __launch_bounds__(256) void k_tail(
    const ushort* __restrict__ x_bf, const ushort* __restrict__ Wcat2,
    const ushort* __restrict__ Wah, const ushort* __restrict__ Wb,
    float* __restrict__ preP, float* __restrict__ hpP, float* __restrict__ gpP,
    int init)
{
  __shared__ ushort As[128 * 72];
  __shared__ ushort Ws[128 * 72];
  int bid = blockIdx.x;
  if (!init && bid < 16) {
    int nt = bid & 3, ks = bid >> 2;
    mfma_body(As, Ws, 0, nt, x_bf + ks * 384, 1536, Wcat2 + ks * 384, 1536, 384,
              0, nullptr, preP + (size_t)ks * 65536, nullptr, 512, 512, nullptr);
    return;
  }
  int j = init ? bid : bid - 16;
  if (j < 8) {
    int nt = j & 3, ks = j >> 2;
    mfma_body(As, Ws, 0, nt, x_bf + 1024 + ks * 256, 1536, Wah + ks * 256, 512,
              256, 0, nullptr, hpP + (size_t)ks * 65536, nullptr, 512, 512, nullptr);
  } else {
    j -= 8;
    int nt = j & 3, ks = j >> 2;
    mfma_body(As, Ws, 0, nt, x_bf + 1024 + ks * 256, 1536, Wb + ks * 256, 512,
              256, 0, nullptr, gpP + (size_t)ks * 65536, nullptr, 512, 512, nullptr);
  }
}

// ---------------------------------------------------------------------------
// Prep: weight conversions. Wg is gate-interleaved: row f*4+g <- orig row
// g*512+f of [W_ih|W_hh]; biascR likewise. Grid-stride.
__global__ __launch_bounds__(256) void k_prep(
    const float* __restrict__ W_ih, const float* __restrict__ W_hh,
    const float* __restrict__ b_ih, const float* __restrict__ b_hh,
    const float* __restrict__ W_y, const float* __restrict__ W_h,
    const float* __restrict__ W_z, const float* __restrict__ W_out,
    const float* __restrict__ W_att_f, const float* __restrict__ W_att_h,
    const float* __restrict__ W_beta, const float* __restrict__ b_att_f,
    const float* __restrict__ b_att_h, const float* __restrict__ ann,
    ushort* __restrict__ Wg, ushort* __restrict__ Wcat2_bf,
    ushort* __restrict__ Wo_bf, ushort* __restrict__ Waf_bf,
    ushort* __restrict__ Wah_bf, ushort* __restrict__ Wb_bf,
    ushort* __restrict__ ann_bf, float* __restrict__ biascR,
    float* __restrict__ b_hf)
{
  int idx = blockIdx.x * 256 + threadIdx.x;
  int stride = gridDim.x * 256;
  for (int i = idx; i < 12845056 / 8; i += stride)
    cvt8(ann + (size_t)i * 8, ann_bf + (size_t)i * 8);
  for (int i = idx; i < 3145728 / 8; i += stride) {
    int k8 = i * 8, rp = k8 / 1536, c = k8 - rp * 1536;
    int f = rp >> 2, g = rp & 3;
    int r = g * 512 + f;
    const float* src = (c < 1024) ? (W_ih + (size_t)r * 1024 + c)
                                  : (W_hh + (size_t)r * 512 + c - 1024);
    cvt8(src, Wg + k8);
  }
  for (int i = idx; i < 786432 / 8; i += stride) {
    int k8 = i * 8, r = k8 / 1536, c = k8 - r * 1536;
    const float* src = (c < 512) ? (W_y + (size_t)r * 512 + c)
                     : (c < 1024 ? (W_z + (size_t)r * 512 + c - 512)
                                 : (W_h + (size_t)r * 512 + c - 1024));
    cvt8(src, Wcat2_bf + k8);
  }
  for (int i = idx; i < 5177344 / 8; i += stride) {   // Wo: 10112x512, pad 0
    int r = i >> 6, c8 = i & 63;
    if (r < 10000) cvt8(W_out + (size_t)r * 512 + c8 * 8, Wo_bf + (size_t)i * 8);
    else { *(uint4*)(Wo_bf + (size_t)i * 8) = make_uint4(0, 0, 0, 0); }
  }
  for (int i = idx; i < 262144 / 8; i += stride) {
    cvt8(W_att_f + i * 8, Waf_bf + i * 8);
    cvt8(W_att_h + i * 8, Wah_bf + i * 8);
    cvt8(W_beta + i * 8, Wb_bf + i * 8);
  }
  for (int i = idx; i < 2048; i += stride) {
    int f = i >> 2, g = i & 3;
    biascR[i] = b_ih[g * 512 + f] + b_hh[g * 512 + f];
  }
  for (int i = idx; i < 512; i += stride) b_hf[i] = b_att_h[i] + b_att_f[i];
}

// mean over L, dec_len
__global__ __launch_bounds__(256) void k_mean(
    const float* __restrict__ ann, const int* __restrict__ lengths,
    float* __restrict__ meanb, int* __restrict__ declen, float* __restrict__ out_dec)
{
  int b = blockIdx.x, tid = threadIdx.x;
  const float* ab = ann + (size_t)b * 196 * 512;
  for (int f = tid; f < 512; f += 256) {
    float s = 0.f;
    for (int l = 0; l < 196; ++l) s += ab[l * 512 + f];
    meanb[b * 512 + f] = s * (1.f / 196.f);
  }
  if (tid == 0) {
    int d = lengths[b] - 1;
    if (d < 1) d = 1;
    declen[b] = d;
    out_dec[b] = (float)d;
  }
}

// fp32 32x64-tile GEMM for h0/c0 init (tiny).
DEV float actf(float v, int act) { return act == 2 ? tanhf(v) : v; }
__global__ __launch_bounds__(256) void gemm32_k(
    const float* __restrict__ A, int lda, const float* __restrict__ W, int ldw,
    const float* __restrict__ bias, float* __restrict__ C, int ldc, int K, int act)
{
  __shared__ float As[32 * 36];
  __shared__ float Ws[32 * 68];
  const int tid = threadIdx.x;
  const int m0 = blockIdx.y * 32, n0 = blockIdx.x * 64;
  const int tx = tid & 15, ty = tid >> 4;
  const int r0 = ty * 2, c0 = tx * 4;
  const int lr = tid >> 3, lk = (tid & 7) * 4;
  const float* Ap = A + (size_t)(m0 + lr) * lda + lk;
  const float* Wp0 = W + (size_t)(n0 + lr) * ldw + lk;
  const float* Wp1 = W + (size_t)(n0 + lr + 32) * ldw + lk;
  float acc[2][4] = {{0.f, 0.f, 0.f, 0.f}, {0.f, 0.f, 0.f, 0.f}};
  for (int k0 = 0; k0 < K; k0 += 32) {
    float4 av = *(const float4*)(Ap + k0);
    float4 w0 = *(const float4*)(Wp0 + k0);
    float4 w1 = *(const float4*)(Wp1 + k0);
    __syncthreads();
    As[(lk + 0) * 36 + lr] = av.x; As[(lk + 1) * 36 + lr] = av.y;
    As[(lk + 2) * 36 + lr] = av.z; As[(lk + 3) * 36 + lr] = av.w;
    Ws[(lk + 0) * 68 + lr] = w0.x; Ws[(lk + 1) * 68 + lr] = w0.y;
    Ws[(lk + 2) * 68 + lr] = w0.z; Ws[(lk + 3) * 68 + lr] = w0.w;
    Ws[(lk + 0) * 68 + lr + 32] = w1.x; Ws[(lk + 1) * 68 + lr + 32] = w1.y;
    Ws[(lk + 2) * 68 + lr + 32] = w1.z; Ws[(lk + 3) * 68 + lr + 32] = w1.w;
    __syncthreads();
#pragma unroll
    for (int kk = 0; kk < 32; ++kk) {
      float2 a = *(const float2*)&As[kk * 36 + r0];
      float4 w = *(const float4*)&Ws[kk * 68 + c0];
      const float aa[2] = {a.x, a.y};
      const float* wwp = (const float*)&w;
#pragma unroll
      for (int i = 0; i < 2; ++i)
#pragma unroll
        for (int j = 0; j < 4; ++j)
          acc[i][j] = fmaf(aa[i], wwp[j], acc[i][j]);
    }
  }
#pragma unroll
  for (int i = 0; i < 2; ++i)
#pragma unroll
    for (int j = 0; j < 4; ++j)
      C[(size_t)(m0 + r0 + i) * ldc + n0 + c0 + j] =
          actf(acc[i][j] + bias[n0 + c0 + j], act);
}

__global__ __launch_bounds__(256) void k_cvt_h0(
    const float* __restrict__ h0f, ushort* __restrict__ x_bf)
{
  int idx = blockIdx.x * 256 + threadIdx.x;   // 65536
  int b = idx >> 9, j = idx & 511;
  x_bf[b * 1536 + 1024 + j] = f2bf(h0f[idx]);
}

// ---------------------------------------------------------------------------
// Attention step (1024 thr): sums hp/gp partials (+biases), combines pre
// partials for step t-1, computes scores/softmax/context, writes x_bf.
__global__ __launch_bounds__(1024) void k_attn(
    const ushort* __restrict__ annp_bf, const ushort* __restrict__ ann_bf,
    const float* __restrict__ hpP, const float* __restrict__ gpP,
    const float* __restrict__ preP,
    const float* __restrict__ b_hf, const float* __restrict__ b_beta,
    const float* __restrict__ wv, const float* __restrict__ bv,
    const int* __restrict__ captions, const float* __restrict__ E_emb,
    const int* __restrict__ declen,
    ushort* __restrict__ x_bf, ushort* __restrict__ preA_bf,
    float* __restrict__ out_alpha, int t)
{
  int b = blockIdx.x, tid = threadIdx.x;
  int lane = tid & 63, wvx = tid >> 6;   // 16 waves
  __shared__ float s_hp[512];
  __shared__ float s_wv[512];
  __shared__ float s_sc[196];
  __shared__ float s_red[32];
  __shared__ float s_ctx[1024];
  if (tid < 512) {
    int o = b * 512 + tid;
    s_hp[tid] = hpP[o] + hpP[65536 + o] + b_hf[tid];
    if (t > 0) {
      float s = preP[o] + preP[65536 + o] + preP[131072 + o] + preP[196608 + o];
      preA_bf[((size_t)(t - 1) * 128 + b) * 512 + tid] = f2bf(tanhf(s));
    }
  } else {
    s_wv[tid - 512] = wv[tid - 512];
  }
  __syncthreads();
  const ushort* ap = annp_bf + (size_t)b * 196 * 512;
  for (int l = wvx; l < 196; l += 16) {
    const ushort* row = ap + l * 512;
    float acc = 0.f;
#pragma unroll
    for (int a0 = 0; a0 < 512; a0 += 256) {
      ushort4 rv = *(const ushort4*)(row + a0 + lane * 4);
      float4 hv = *(const float4*)&s_hp[a0 + lane * 4];
      float4 wt = *(const float4*)&s_wv[a0 + lane * 4];
      acc = fmaf(fmaxf(bf2f(rv.x) + hv.x, 0.f), wt.x, acc);
      acc = fmaf(fmaxf(bf2f(rv.y) + hv.y, 0.f), wt.y, acc);
      acc = fmaf(fmaxf(bf2f(rv.z) + hv.z, 0.f), wt.z, acc);
      acc = fmaf(fmaxf(bf2f(rv.w) + hv.w, 0.f), wt.w, acc);
    }
    for (int off = 32; off; off >>= 1) acc += __shfl_xor(acc, off, 64);
    if (lane == 0) s_sc[l] = acc + bv[0];
  }
  __syncthreads();
  float v = (tid < 196) ? s_sc[tid] : -3.402823466e38f;
  float m = v;
  for (int off = 32; off; off >>= 1) m = fmaxf(m, __shfl_xor(m, off, 64));
  if (lane == 0) s_red[wvx] = m;
  __syncthreads();
  m = s_red[0];
#pragma unroll
  for (int i = 1; i < 16; ++i) m = fmaxf(m, s_red[i]);
  float e = (tid < 196) ? expf(v - m) : 0.f;
  float s = e;
  for (int off = 32; off; off >>= 1) s += __shfl_xor(s, off, 64);
  if (lane == 0) s_red[16 + wvx] = s;
  __syncthreads();
  s = 0.f;
#pragma unroll
  for (int i = 0; i < 16; ++i) s += s_red[16 + i];
  float inv = 1.f / s;
  bool active = t < declen[b];
  if (tid < 196) {
    float al = e * inv;
    s_sc[tid] = al;
    out_alpha[((size_t)b * 31 + t) * 196 + tid] = active ? al : 0.f;
  }
  __syncthreads();
  // context: threads split into two halves over l
  int half = tid >> 9, f = tid & 511;
  const ushort* ab = ann_bf + (size_t)b * 196 * 512 + (size_t)half * 98 * 512 + f;
  const float* scp = &s_sc[half * 98];
  float ctx = 0.f;
#pragma unroll 7
  for (int l = 0; l < 98; ++l) ctx = fmaf(scp[l], bf2f(ab[(size_t)l * 512]), ctx);
  s_ctx[tid] = ctx;
  __syncthreads();
  if (tid < 512) {
    float cv = s_ctx[tid] + s_ctx[tid + 512];
    int o = b * 512 + tid;
    float g = sigmf(gpP[o] + gpP[65536 + o] + b_beta[tid]);
    x_bf[b * 1536 + 512 + tid] = f2bf(g * cv);
  } else {
    int e2 = tid - 512;
    int tok = captions[b * 32 + t];
    x_bf[b * 1536 + e2] = f2bf(E_emb[(size_t)tok * 512 + e2]);
  }
}

// LSTM pointwise: sums 4 gate partials (gate-interleaved float4) + bias.
__global__ __launch_bounds__(256) void k_lstm(
    const float* __restrict__ gP, const float* __restrict__ biascR,
    float* __restrict__ c, ushort* __restrict__ x_bf,
    const int* __restrict__ declen, int t)
{
  int idx = blockIdx.x * 256 + threadIdx.x;   // 65536
  int b = idx >> 9, f = idx & 511;
  if (t >= declen[b]) return;
  float4 v = make_float4(0.f, 0.f, 0.f, 0.f);
#pragma unroll
  for (int ks = 0; ks < 4; ++ks) {
    float4 pv = *(const float4*)&gP[(size_t)ks * 262144 + b * 2048 + f * 4];
    v.x += pv.x; v.y += pv.y; v.z += pv.z; v.w += pv.w;
  }
  float4 bc = *(const float4*)&biascR[f * 4];
  float i_ = v.x + bc.x, f_ = v.y + bc.y, g_ = v.z + bc.z, o_ = v.w + bc.w;
  float cn = sigmf(f_) * c[idx] + sigmf(i_) * tanhf(g_);
  float hn = sigmf(o_) * tanhf(cn);
  c[idx] = cn;
  x_bf[b * 1536 + 1024 + f] = f2bf(hn);
}

// Final pre-combine for t=30.
__global__ __launch_bounds__(512) void k_comb30(
    const float* __restrict__ preP, ushort* __restrict__ preA_bf)
{
  int b = blockIdx.x, f = threadIdx.x;
  int o = b * 512 + f;
  float s = preP[o] + preP[65536 + o] + preP[131072 + o] + preP[196608 + o];
  preA_bf[((size_t)30 * 128 + b) * 512 + f] = f2bf(tanhf(s));
}

// ---------------------------------------------------------------------------
extern "C" void kernel_launch(void* const* d_in, const int* in_sizes, int n_in,
                              void* d_out, int out_size, void* d_ws, size_t ws_size,
                              hipStream_t stream)
{
  const float* ann      = (const float*)d_in[0];
  const int*   captions = (const int*)d_in[1];
  const int*   lengths  = (const int*)d_in[2];
  const float* E_emb    = (const float*)d_in[3];
  const float* W_init_h = (const float*)d_in[4];
  const float* b_init_h = (const float*)d_in[5];
  const float* W_init_c = (const float*)d_in[6];
  const float* b_init_c = (const float*)d_in[7];
  const float* W_att_f  = (const float*)d_in[8];
  const float* b_att_f  = (const float*)d_in[9];
  const float* W_att_h  = (const float*)d_in[10];
  const float* b_att_h  = (const float*)d_in[11];
  const float* w_att_v  = (const float*)d_in[12];
  const float* b_att_v  = (const float*)d_in[13];
  const float* W_beta   = (const float*)d_in[14];
  const float* b_beta   = (const float*)d_in[15];
  const float* W_ih     = (const float*)d_in[16];
  const float* W_hh     = (const float*)d_in[17];
  const float* b_ih     = (const float*)d_in[18];
  const float* b_hh     = (const float*)d_in[19];
  const float* W_y      = (const float*)d_in[20];
  const float* W_h      = (const float*)d_in[21];
  const float* W_z      = (const float*)d_in[22];
  const float* W_out    = (const float*)d_in[23];
  const float* b_out    = (const float*)d_in[24];

  float* out        = (float*)d_out;
  float* out_logits = out;
  float* out_alpha  = out + 39680000ll;
  float* out_dec    = out + 40457728ll;

  char* p = (char*)d_ws;
  auto alloc_us = [&](size_t n) { ushort* r = (ushort*)p; p += ((n * 2 + 255) & ~(size_t)255); return r; };
  auto alloc_f  = [&](size_t n) { float*  r = (float*)p;  p += ((n * 4 + 255) & ~(size_t)255); return r; };
  ushort* Wo_bf    = alloc_us(10112 * 512);
  ushort* Wg_bf    = alloc_us(2048 * 1536);
  ushort* Wcat2_bf = alloc_us(512 * 1536);
  ushort* Waf_bf   = alloc_us(512 * 512);
  ushort* Wah_bf   = alloc_us(512 * 512);
  ushort* Wb_bf    = alloc_us(512 * 512);
  ushort* ann_bf   = alloc_us(12845056);
  ushort* annp_bf  = alloc_us(12845056);
  ushort* preA_bf  = alloc_us(3968 * 512);
  ushort* x_bf     = alloc_us(128 * 1536);
  float* biascR = alloc_f(2048);
  float* b_hf   = alloc_f(512);
  float* hpP    = alloc_f(2 * 65536);
  float* gpP    = alloc_f(2 * 65536);
  float* preP   = alloc_f(4 * 65536);
  float* gP     = alloc_f(4 * 262144);
  float* cbuf   = alloc_f(65536);
  float* meanb  = alloc_f(65536);
  float* h0f    = alloc_f(65536);
  int*   declen = (int*)alloc_f(128);

  // ---- phase 1 ----
  hipLaunchKernelGGL(k_prep, dim3(1024), dim3(256), 0, stream,
                     W_ih, W_hh, b_ih, b_hh, W_y, W_h, W_z, W_out,
                     W_att_f, W_att_h, W_beta, b_att_f, b_att_h, ann,
                     Wg_bf, Wcat2_bf, Wo_bf, Waf_bf, Wah_bf, Wb_bf, ann_bf,
                     biascR, b_hf);
  hipLaunchKernelGGL(k_mean, dim3(128), dim3(256), 0, stream,
                     ann, lengths, meanb, declen, out_dec);
  hipLaunchKernelGGL(gemm32_k, dim3(8, 4), dim3(256), 0, stream,
                     meanb, 512, W_init_h, 512, b_init_h, h0f, 512, 512, 2);
  hipLaunchKernelGGL(gemm32_k, dim3(8, 4), dim3(256), 0, stream,
                     meanb, 512, W_init_c, 512, b_init_c, cbuf, 512, 512, 2);
  hipLaunchKernelGGL(k_cvt_h0, dim3(256), dim3(256), 0, stream, h0f, x_bf);
  hipLaunchKernelGGL(k_mfma, dim3(4, 196), dim3(256), 0, stream,
                     ann_bf, 512, Waf_bf, 512, 512, 1, (const float*)nullptr,
                     (float*)nullptr, annp_bf, 512, 512, (const int*)nullptr);
  hipLaunchKernelGGL(k_tail, dim3(16), dim3(256), 0, stream,
                     x_bf, Wcat2_bf, Wah_bf, Wb_bf, preP, hpP, gpP, 1);

  // ---- phase 2: 31 steps ----
  for (int t = 0; t < 31; ++t) {
    hipLaunchKernelGGL(k_attn, dim3(128), dim3(1024), 0, stream,
                       annp_bf, ann_bf, hpP, gpP, preP, b_hf, b_beta,
                       w_att_v, b_att_v, captions, E_emb, declen,
                       x_bf, preA_bf, out_alpha, t);
    hipLaunchKernelGGL(k_gates, dim3(64), dim3(256), 0, stream,
                       x_bf, Wg_bf, gP);
    hipLaunchKernelGGL(k_lstm, dim3(256), dim3(256), 0, stream,
                       gP, biascR, cbuf, x_bf, declen, t);
    hipLaunchKernelGGL(k_tail, dim3(32), dim3(256), 0, stream,
                       x_bf, Wcat2_bf, Wah_bf, Wb_bf,
                       preP, hpP, gpP, 0);
  }

  // ---- phase 3 ----
  hipLaunchKernelGGL(k_comb30, dim3(128), dim3(512), 0, stream, preP, preA_bf);
  hipLaunchKernelGGL(k_logits, dim3(2480), dim3(256), 0, stream,
                     preA_bf, Wo_bf, b_out, out_logits, declen);
}